// Round 3
// baseline (483.280 us; speedup 1.0000x reference)
//
#include <hip/hip_runtime.h>
#include <cstdint>

// GARCH scan: B=64, T=2000, F=257, fp32.
//
// v5 = v4 (verified-correct register-ring consumer, 197 us, VALUBusy 9%)
//      + per-block L2-warmer wave.
// v4 diagnosis: latency-bound. VGPR_Count=88 proves the 24-slot v4 ring
// (needs >=92 VGPRs payload) was shortened by regalloc -> effective ~5
// chunks in flight against ~900cyc HBM latency -> ~470 cyc/chunk.
// Fix: wave 1 prefetches chunks 24..999 into L2, throttled to <=48 chunks
// ahead of the consumer via an LDS progress counter (48 KB/block ahead;
// 40 blocks/XCD * 48KB = 1.9 MB << 4 MB L2). Consumer then sees ~250cyc
// L2 latency -> compute-chain-bound (~70-90 cyc/chunk). Warmer results
// are discarded; consumer logic is UNCHANGED except the progress store.

#define GB 64
#define GT 2000
#define GF 257
#define GEPS 1e-7f

constexpr int S2f   = 2 * GF;        // 514 floats per input row
constexpr int ROWB  = S2f * 4;       // 2056 B input row
constexpr int OROWB = GF * 4;        // 1028 B output row
constexpr int NCH   = GT / 2;        // 1000 chunks of 2 rows
constexpr int RB    = 24;            // register ring slots
constexpr int UNROLL = 24;           // inner unroll = RB (static indices)
constexpr int AHEAD = 48;            // warmer throttle (chunks ahead)

typedef float v4f  __attribute__((ext_vector_type(4)));
typedef float v4fu __attribute__((ext_vector_type(4), aligned(4)));

// one recurrence step; uses a, am1, be, g, e, pw, s0, s1 from scope
#define STEP(mg, pp, cv)                                                  \
  {                                                                       \
    float msq_ = (mg) * (mg);                                             \
    float u_   = fmaf(am1, msq_, a * s0);                                 \
    float v_   = fmaf(e, s0, fmaf(g, s1, be));                            \
    float ns_  = fmaf(u_, 1.0f - (pp), v_ * (pp));                        \
    float cc_  = (mg) - __builtin_amdgcn_sqrtf(ns_ + GEPS);               \
    cc_ = fmaxf(cc_, 0.0f);                                               \
    s1 = fmaxf(fmaf(-pw, cc_ * cc_, msq_), 0.0f);                        \
    s0 = ns_;                                                             \
    (cv) = cc_;                                                           \
  }

__global__ __launch_bounds__(128) void garch_kernel(
    const float* __restrict__ in,
    const float* __restrict__ Alpha,
    const float* __restrict__ beta,
    const float* __restrict__ gamma,
    const float* __restrict__ eta,
    const float* __restrict__ pi,
    float* __restrict__ out)
{
  __shared__ v4f lring[4][64];                 // input transpose ring, 4 KB
  __shared__ __align__(16) float ob[512];      // output staging, 2 KB
  __shared__ float td[2 * GT];                 // tail staging, 16 KB
  __shared__ uint32_t prog;                    // consumer progress (chunks)

  const int tid  = threadIdx.x;
  const int w    = tid >> 6;                   // wave id (0=consumer,1=warmer)
  const int lane = tid & 63;
  const int blk  = blockIdx.x;

  if (blk < 256) {
    // ------------- main path: 64 chains (b, f0..f0+63) -------------
    const int b  = blk >> 2;
    const int f0 = (blk & 3) << 6;

    // shared chunk-address mapping (both waves): 1KB chunk = 2 rows;
    // sub=lane>>4 selects {mag r0, p r0, mag r1, p r1}; q=lane&15 16B slice
    const uint8_t* gb = (const uint8_t*)in + (size_t)b * GT * ROWB;
    const int sub = lane >> 4;
    const int q   = lane & 15;
    const uint8_t* gsrc = gb + (size_t)(sub >> 1) * ROWB
                             + (size_t)(sub & 1) * (GF * 4)
                             + (size_t)f0 * 4 + (size_t)q * 16;

    if (tid == 0) prog = 0;
    __syncthreads();                           // prog visible to both waves

    if (w == 0) {
      // =================== consumer wave (v4 code) ===================
      const int f = f0 + lane;
      const float a   = Alpha[f];
      const float be  = beta[f];
      const float g   = gamma[f];
      const float e   = eta[f];
      const float pw  = pi[f];
      const float am1 = 1.0f - a;

      const float* lc0 = (const float*)&lring[0][0];  // slot stride 256 f

      uint8_t* stp = (uint8_t*)out + (size_t)b * GT * OROWB
                   + (size_t)(lane >> 4) * OROWB
                   + (size_t)f0 * 4 + (size_t)q * 16;

      v4fu rb[RB];
      // prologue: chunks 2..24 into rb (slots c%24); chunks 0,1 -> LDS
      #pragma unroll
      for (int c = 2; c <= 24; ++c)
        rb[c % RB] = *(const v4fu*)(gsrc + (size_t)c * (2 * ROWB));
      {
        v4fu t0 = *(const v4fu*)(gsrc);
        v4fu t1 = *(const v4fu*)(gsrc + (size_t)(2 * ROWB));
        lring[0][lane] = t0;
        lring[1][lane] = t1;
      }

      float s0 = 0.0f, s1 = 0.0f;

      for (int sbi = 0; sbi < 1008; sbi += UNROLL) {
        #pragma unroll
        for (int u = 0; u < UNROLL; ++u) {
          const int s = sbi + u;
          // A: prefetch
          if (s + 25 < NCH)
            rb[(u + 1) % RB] =
                *(const v4fu*)(gsrc + (size_t)(s + 25) * (2 * ROWB));
          __builtin_amdgcn_sched_barrier(0);
          // C: consume chunk s (rows 2s, 2s+1)
          if (s < NCH) {
            if ((u & 7) == 0 && lane == 0)      // publish progress
              __hip_atomic_store(&prog, (uint32_t)s, __ATOMIC_RELAXED,
                                 __HIP_MEMORY_SCOPE_WORKGROUP);
            const float* lc = lc0 + (size_t)(u & 3) * 256;
            const float mg0 = lc[lane];
            const float p0  = lc[64 + lane];
            const float mg1 = lc[128 + lane];
            const float p1  = lc[192 + lane];
            if (s == 0) {                       // carry init from t=0 inputs
              float t = mg0 * (1.0f - p0);
              s0 = s1 = t * t;
            }
            float c0, c1;
            STEP(mg0, p0, c0);
            STEP(mg1, p1, c1);
            const int h = (u >> 1) & 1;
            ob[h * 256 + (u & 1) * 128 + lane]      = c0;
            ob[h * 256 + (u & 1) * 128 + 64 + lane] = c1;
            if ((u & 1) && s >= 3) {            // flush previous group
              v4f od = ((const v4f*)ob)[(1 - h) * 64 + lane];
              *(v4fu*)stp = od;
              stp += 4 * OROWB;
            }
          }
          // B: stage chunk s+2 into LDS ring
          if (s + 2 < NCH)
            lring[(u + 2) & 3][lane] = rb[(u + 2) % RB];
        }
      }
      // epilogue: flush last group (rows 1996..1999, half 1)
      {
        v4f od = ((const v4f*)ob)[64 + lane];
        *(v4fu*)stp = od;
      }
    } else {
      // =================== warmer wave: L2 prefetch ===================
      for (int c = 24; c < NCH; ++c) {
        // throttle: stay <= AHEAD chunks ahead of consumer
        while (true) {
          uint32_t pr = __hip_atomic_load(&prog, __ATOMIC_RELAXED,
                                          __HIP_MEMORY_SCOPE_WORKGROUP);
          if (c - (int)pr <= AHEAD) break;
          __builtin_amdgcn_s_sleep(2);
        }
        v4f dummy;
        asm volatile("global_load_dwordx4 %0, %1, off"
                     : "=v"(dummy)
                     : "v"((uint64_t)(uintptr_t)(gsrc +
                            (size_t)c * (2 * ROWB))));
      }
      // no waits: results discarded; vmcnt backpressure self-limits
    }
  } else {
    // ------------- tail path: chain (b, f=256) -------------
    const int b = blk - 256;
    const float* prow = in + (size_t)b * GT * S2f;

    // phase 1: gather (mag,p)[f=256] for all rows, 128 threads
    float mreg[16], preg[16];
    #pragma unroll
    for (int k = 0; k < 16; ++k) {
      const int t = tid + (k << 7);
      if (t < GT) {
        mreg[k] = prow[(size_t)t * S2f + (GF - 1)];
        preg[k] = prow[(size_t)t * S2f + (2 * GF - 1)];
      }
    }
    #pragma unroll
    for (int k = 0; k < 16; ++k) {
      const int t = tid + (k << 7);
      if (t < GT) {
        td[2 * t]     = mreg[k];
        td[2 * t + 1] = preg[k];
      }
    }
    __syncthreads();

    if (tid < 64) {
      const float a   = Alpha[GF - 1];
      const float be  = beta[GF - 1];
      const float g   = gamma[GF - 1];
      const float e   = eta[GF - 1];
      const float pw  = pi[GF - 1];
      const float am1 = 1.0f - a;

      float m0 = td[0], p0 = td[1];
      float tt = m0 * (1.0f - p0);
      float s0 = tt * tt, s1 = s0;

      for (int j = 0; j < GT / 16; ++j) {
        float mv[16], pv[16];
        #pragma unroll
        for (int r = 0; r < 16; ++r) {
          mv[r] = td[2 * (16 * j + r)];
          pv[r] = td[2 * (16 * j + r) + 1];
        }
        float creg = 0.0f;
        #pragma unroll
        for (int r = 0; r < 16; ++r) {
          float cc;
          STEP(mv[r], pv[r], cc);
          if (tid == r) creg = cc;
        }
        if (tid < 16)
          out[((size_t)(b * GT + 16 * j + tid)) * GF + (GF - 1)] = creg;
      }
    }
  }
}

extern "C" void kernel_launch(void* const* d_in, const int* in_sizes, int n_in,
                              void* d_out, int out_size, void* d_ws, size_t ws_size,
                              hipStream_t stream) {
  const float* in    = (const float*)d_in[0];
  const float* Alpha = (const float*)d_in[1];
  const float* beta  = (const float*)d_in[2];
  const float* gamma = (const float*)d_in[3];
  const float* eta   = (const float*)d_in[4];
  const float* pi    = (const float*)d_in[5];
  float* out = (float*)d_out;

  // 256 main blocks (b, 64-f group) + 64 tail blocks (f=256)
  garch_kernel<<<320, 128, 0, stream>>>(in, Alpha, beta, gamma, eta, pi, out);
}